// Round 3
// baseline (107.919 us; speedup 1.0000x reference)
//
#include <hip/hip_runtime.h>
#include <math.h>

constexpr int NCAPS = 1152;
constexpr int CIN   = 8;
constexpr int COUT  = 16;
constexpr int BATCH = 128;
constexpr int DCAPS = 10;
constexpr int NTHREADS = 768;        // 12 waves
constexpr int NWAVES = NTHREADS / 64;
constexpr int QPT = NCAPS * 4 / NTHREADS;   // 6 o-quads per thread

// One block per (d,b). Lane = nsub*4 + oq: a w-load instruction reads 16
// segments of 64 contiguous B (4 lanes x float4) -> 16 lines/instr, each line
// consumed exactly once. QPT=6 keeps u4 at 24 VGPRs (R2's QPT=12 spilled:
// WRITE_SIZE 13.5 MB of scratch). exp is fused into the s-accumulation so no
// cc[] array is materialized. launch_bounds(768,6): 2 blocks/CU resident.
__global__ __launch_bounds__(NTHREADS, 6) void digitcaps_kernel(
    const float* __restrict__ x,    // [128, 1152, 8]
    const float* __restrict__ w,    // [10, 1152, 8, 16]
    float* __restrict__ out)        // [10, 128, 16]
{
    __shared__ float4 red[NWAVES][4];   // per-wave partial s, by oq
    __shared__ float  sbuf[NWAVES];     // softmax max / sum partials
    __shared__ float4 vsh[4];           // squashed v, by oq

    // XCD swizzle: block i -> XCD (i&7); each XCD gets a 5d x 32b rectangle
    // (L2 footprint ~4 MB: 5 w-slices + 32 x-slices).
    const int i   = blockIdx.x;
    const int xcd = i & 7;
    const int k   = i >> 3;                    // 0..159
    const int d   = (xcd >> 2) * 5 + (k % 5);  // 0..9
    const int b   = (k / 5) * 4 + (xcd & 3);   // 0..127

    const int t    = threadIdx.x;
    const int wave = t >> 6;
    const int lane = t & 63;
    const int nsub = lane >> 2;   // 0..15: row within the wave's 16-row group
    const int oq   = lane & 3;    // 0..3:  o-quad

    const float* xb = x + (size_t)b * NCAPS * CIN;
    const float* wd = w + (size_t)d * NCAPS * CIN * COUT + oq * 4;

    // ---- u4[j] = x[b,n,:] . w[d,n,:,4oq..4oq+3],  n = j*192 + wave*16 + nsub
    float4 u4[QPT];
    #pragma unroll
    for (int j = 0; j < QPT; ++j) {
        const int n = j * 192 + wave * 16 + nsub;
        const float4* xr = (const float4*)(xb + (size_t)n * CIN);
        float4 xa = xr[0];
        float4 xc = xr[1];
        const float* wr = wd + (size_t)n * CIN * COUT;
        float4 w0 = *(const float4*)(wr + 0 * COUT);
        float4 w1 = *(const float4*)(wr + 1 * COUT);
        float4 w2 = *(const float4*)(wr + 2 * COUT);
        float4 w3 = *(const float4*)(wr + 3 * COUT);
        float4 w4 = *(const float4*)(wr + 4 * COUT);
        float4 w5 = *(const float4*)(wr + 5 * COUT);
        float4 w6 = *(const float4*)(wr + 6 * COUT);
        float4 w7 = *(const float4*)(wr + 7 * COUT);
        float4 acc;
        acc.x = xa.x * w0.x; acc.y = xa.x * w0.y;
        acc.z = xa.x * w0.z; acc.w = xa.x * w0.w;
        acc.x = fmaf(xa.y, w1.x, acc.x); acc.y = fmaf(xa.y, w1.y, acc.y);
        acc.z = fmaf(xa.y, w1.z, acc.z); acc.w = fmaf(xa.y, w1.w, acc.w);
        acc.x = fmaf(xa.z, w2.x, acc.x); acc.y = fmaf(xa.z, w2.y, acc.y);
        acc.z = fmaf(xa.z, w2.z, acc.z); acc.w = fmaf(xa.z, w2.w, acc.w);
        acc.x = fmaf(xa.w, w3.x, acc.x); acc.y = fmaf(xa.w, w3.y, acc.y);
        acc.z = fmaf(xa.w, w3.z, acc.z); acc.w = fmaf(xa.w, w3.w, acc.w);
        acc.x = fmaf(xc.x, w4.x, acc.x); acc.y = fmaf(xc.x, w4.y, acc.y);
        acc.z = fmaf(xc.x, w4.z, acc.z); acc.w = fmaf(xc.x, w4.w, acc.w);
        acc.x = fmaf(xc.y, w5.x, acc.x); acc.y = fmaf(xc.y, w5.y, acc.y);
        acc.z = fmaf(xc.y, w5.z, acc.z); acc.w = fmaf(xc.y, w5.w, acc.w);
        acc.x = fmaf(xc.z, w6.x, acc.x); acc.y = fmaf(xc.z, w6.y, acc.y);
        acc.z = fmaf(xc.z, w6.z, acc.z); acc.w = fmaf(xc.z, w6.w, acc.w);
        acc.x = fmaf(xc.w, w7.x, acc.x); acc.y = fmaf(xc.w, w7.y, acc.y);
        acc.z = fmaf(xc.w, w7.z, acc.z); acc.w = fmaf(xc.w, w7.w, acc.w);
        u4[j] = acc;
    }

    float bb[QPT];
    #pragma unroll
    for (int j = 0; j < QPT; ++j) bb[j] = 0.f;

    #pragma unroll
    for (int it = 0; it < 3; ++it) {
        float4 p = {0.f, 0.f, 0.f, 0.f};
        float z = 0.f;
        if (it == 0) {
            #pragma unroll
            for (int j = 0; j < QPT; ++j) {
                p.x += u4[j].x; p.y += u4[j].y;
                p.z += u4[j].z; p.w += u4[j].w;
            }
        } else {
            // block max of the logits
            float m = bb[0];
            #pragma unroll
            for (int j = 1; j < QPT; ++j) m = fmaxf(m, bb[j]);
            #pragma unroll
            for (int off = 1; off < 64; off <<= 1)
                m = fmaxf(m, __shfl_xor(m, off));
            if (lane == 0) sbuf[wave] = m;
            __syncthreads();
            float M = sbuf[0];
            #pragma unroll
            for (int wv = 1; wv < NWAVES; ++wv) M = fmaxf(M, sbuf[wv]);
            __syncthreads();
            // fused exp + weighted accumulate (no cc[] array)
            #pragma unroll
            for (int j = 0; j < QPT; ++j) {
                float e = __expf(bb[j] - M);
                z += e;
                p.x = fmaf(e, u4[j].x, p.x);
                p.y = fmaf(e, u4[j].y, p.y);
                p.z = fmaf(e, u4[j].z, p.z);
                p.w = fmaf(e, u4[j].w, p.w);
            }
            z += __shfl_xor(z, 1);
            z += __shfl_xor(z, 2);
        }
        // reduce p across the 16 row-groups (lane bits 2..5); ride z along
        #pragma unroll
        for (int off = 4; off < 64; off <<= 1) {
            p.x += __shfl_xor(p.x, off);
            p.y += __shfl_xor(p.y, off);
            p.z += __shfl_xor(p.z, off);
            p.w += __shfl_xor(p.w, off);
            if (it != 0) z += __shfl_xor(z, off);
        }
        if (nsub == 0) red[wave][oq] = p;
        if (it != 0 && lane == 0) sbuf[wave] = z;
        __syncthreads();

        if (t < 4) {   // t == oq: combine waves, squash, publish v
            float4 s = red[0][t];
            #pragma unroll
            for (int wv = 1; wv < NWAVES; ++wv) {
                float4 r = red[wv][t];
                s.x += r.x; s.y += r.y; s.z += r.z; s.w += r.w;
            }
            float scale;
            if (it == 0) {
                scale = 1.f / (float)NCAPS;
            } else {
                float Z = sbuf[0];
                #pragma unroll
                for (int wv = 1; wv < NWAVES; ++wv) Z += sbuf[wv];
                scale = 4.f / Z;   // each n replicated on 4 oq lanes
            }
            s.x *= scale; s.y *= scale; s.z *= scale; s.w *= scale;
            float4 v;
            v.x = s.x * fabsf(s.x) / (1.f + s.x * s.x);
            v.y = s.y * fabsf(s.y) / (1.f + s.y * s.y);
            v.z = s.z * fabsf(s.z) / (1.f + s.z * s.z);
            v.w = s.w * fabsf(s.w) / (1.f + s.w * s.w);
            vsh[t] = v;
            if (it == 2)
                ((float4*)(out + ((size_t)d * BATCH + b) * COUT))[t] = v;
        }
        __syncthreads();

        if (it < 2) {
            float4 v = vsh[oq];
            #pragma unroll
            for (int j = 0; j < QPT; ++j) {
                float dotv = u4[j].x * v.x + u4[j].y * v.y +
                             u4[j].z * v.z + u4[j].w * v.w;
                dotv += __shfl_xor(dotv, 1);   // sum the 4 oq-lanes of row n
                dotv += __shfl_xor(dotv, 2);
                bb[j] += dotv;
            }
        }
    }
}

extern "C" void kernel_launch(void* const* d_in, const int* in_sizes, int n_in,
                              void* d_out, int out_size, void* d_ws, size_t ws_size,
                              hipStream_t stream) {
    const float* x = (const float*)d_in[0];
    const float* w = (const float*)d_in[1];
    float* out = (float*)d_out;
    digitcaps_kernel<<<DCAPS * BATCH, NTHREADS, 0, stream>>>(x, w, out);
}